// Round 1
// baseline (306.325 us; speedup 1.0000x reference)
//
#include <hip/hip_runtime.h>
#include <math.h>

// Problem constants (fixed by the reference)
#define BN_NODES 16384     // B*N
#define DIM 128            // D
#define HID 256            // H
#define TK 2048            // distance-table knots
#define TRANGE 32.0f
#define TSTEP (TRANGE / (float)TK)   // 1/64
#define TINV  ((float)TK / TRANGE)   // 64
#define LN_EPS 1e-5f
#define NT 16              // nodes per block in node_kernel
#define STR 17             // padded LDS stride (odd -> conflict-free transpose writes)

// ---------------------------------------------------------------------------
// K1: build distance-filter table  T[k][d] = silu(dist_k*W1+b1) @ W2 + b2
// dist_k = k * TSTEP. One block = 8 k-values, 256 threads.
__global__ void build_table(const float* __restrict__ W1, const float* __restrict__ b1,
                            const float* __restrict__ W2, const float* __restrict__ b2,
                            float* __restrict__ T) {
    __shared__ float a[8][HID];     // silu activations, 8 KB
    __shared__ float part[8][DIM];  // partial sums from hg=1, 4 KB
    int t = threadIdx.x;
    int k0 = blockIdx.x * 8;
    // phase A: thread t <-> h = t
    float w1 = W1[t], bb = b1[t];
#pragma unroll
    for (int k = 0; k < 8; ++k) {
        float dist = (float)(k0 + k) * TSTEP;
        float z = dist * w1 + bb;
        a[k][t] = z / (1.0f + expf(-z));
    }
    __syncthreads();
    int hg = t >> 7;     // 0..1  (half of H)
    int d  = t & 127;
    float acc[8] = {0.f,0.f,0.f,0.f,0.f,0.f,0.f,0.f};
    int hbase = hg * 128;
    for (int hh = 0; hh < 128; ++hh) {
        int hidx = hbase + hh;
        float w = W2[hidx * DIM + d];
#pragma unroll
        for (int k = 0; k < 8; ++k) acc[k] += a[k][hidx] * w;
    }
    if (hg == 1) {
#pragma unroll
        for (int k = 0; k < 8; ++k) part[k][d] = acc[k];
    }
    __syncthreads();
    if (hg == 0) {
        float bd = b2[d];
#pragma unroll
        for (int k = 0; k < 8; ++k)
            T[(k0 + k) * DIM + d] = acc[k] + part[k][d] + bd;
    }
}

// ---------------------------------------------------------------------------
// K2: histogram of destination (row) nodes
__global__ void hist_kernel(const int* __restrict__ ei, int* __restrict__ counts, int nE) {
    int e = blockIdx.x * blockDim.x + threadIdx.x;
    if (e < nE) atomicAdd(&counts[ei[e]], 1);
}

// ---------------------------------------------------------------------------
// K3: single-block exclusive scan over 16384 counts -> offsets, cursor
__global__ void scan_kernel(const int* __restrict__ counts, int* __restrict__ offsets,
                            int* __restrict__ cursor) {
    __shared__ int s[256];
    int t = threadIdx.x;
    int base = t * 64;
    int sum = 0;
    for (int i = 0; i < 64; ++i) sum += counts[base + i];
    s[t] = sum;
    __syncthreads();
    for (int off = 1; off < 256; off <<= 1) {
        int v = (t >= off) ? s[t - off] : 0;
        __syncthreads();
        s[t] += v;
        __syncthreads();
    }
    int run = (t == 0) ? 0 : s[t - 1];
    for (int i = 0; i < 64; ++i) {
        int c = counts[base + i];
        offsets[base + i] = run;
        cursor[base + i]  = run;
        run += c;
    }
    if (t == 255) offsets[BN_NODES] = run;
}

// ---------------------------------------------------------------------------
// K4: scatter edges into CSR slots; compute dist per edge
__global__ void scatter_kernel(const int* __restrict__ ei, const float* __restrict__ x,
                               int* __restrict__ cursor, int* __restrict__ eidx,
                               float* __restrict__ edist, int nE) {
    int e = blockIdx.x * blockDim.x + threadIdx.x;
    if (e >= nE) return;
    int r = ei[e];
    int c = ei[nE + e];
    float dx = x[r * 3 + 0] - x[c * 3 + 0];
    float dy = x[r * 3 + 1] - x[c * 3 + 1];
    float dz = x[r * 3 + 2] - x[c * 3 + 2];
    float dist = sqrtf(dx * dx + dy * dy + dz * dz);
    int pos = atomicAdd(&cursor[r], 1);
    eidx[pos]  = c;
    edist[pos] = dist;
}

// ---------------------------------------------------------------------------
// K5: per-node gather + table-interp filter + mean.  One wave per node.
__global__ __launch_bounds__(256) void agg_kernel(
        const int* __restrict__ offsets, const int* __restrict__ eidx,
        const float* __restrict__ edist, const float* __restrict__ h,
        const float* __restrict__ T, float* __restrict__ agg) {
    int wave = threadIdx.x >> 6;
    int lane = threadIdx.x & 63;
    int node = blockIdx.x * 4 + wave;
    int off0 = offsets[node], off1 = offsets[node + 1];
    float a0 = 0.f, a1 = 0.f;
    int dd = lane * 2;
    for (int s = off0; s < off1; ++s) {
        int c = eidx[s];          // wave-uniform load (broadcast via cache)
        float dist = edist[s];
        float u = dist * TINV;
        int k = (int)u;
        k = min(k, TK - 2);
        float frac = u - (float)k;
        const float* t0 = &T[k * DIM + dd];
        float2 T0 = *(const float2*)t0;
        float2 T1 = *(const float2*)(t0 + DIM);
        float2 hv = *(const float2*)&h[c * DIM + dd];
        float f0 = T0.x + (T1.x - T0.x) * frac;
        float f1 = T0.y + (T1.y - T0.y) * frac;
        a0 += hv.x * f0;
        a1 += hv.y * f1;
    }
    int deg = off1 - off0;
    float inv = 1.0f / (float)max(deg, 1);
    float2 res; res.x = a0 * inv; res.y = a1 * inv;
    *(float2*)&agg[node * DIM + dd] = res;
}

// ---------------------------------------------------------------------------
// K6: fused node update: u = [h,agg]@W3+b3 -> LN -> SiLU -> @W4+b4
// 16 nodes per block, 256 threads, register-tiled 4x4 / 4x2.
__global__ __launch_bounds__(256) void node_kernel(
        const float* __restrict__ h, const float* __restrict__ agg,
        const float* __restrict__ W3, const float* __restrict__ b3,
        const float* __restrict__ gamma, const float* __restrict__ beta,
        const float* __restrict__ W4, const float* __restrict__ b4,
        float* __restrict__ out) {
    __shared__ float in_t[256 * STR];   // transposed [i][node], 17 KB; reused for act
    __shared__ float w_tile[32 * 256];  // 32 KB: W3 chunk [32][256] or W4 chunk [64][128]
    int t = threadIdx.x;
    int n0 = blockIdx.x * NT;

    // phase 1: load concat(h, agg) transposed into LDS
    for (int rep = 0; rep < NT; ++rep) {
        int node = n0 + rep;
        float v = (t < 128) ? h[node * DIM + t] : agg[node * DIM + (t - 128)];
        in_t[t * STR + rep] = v;
    }

    int jg = t & 63, ng = t >> 6;
    int jb = jg * 4, nb = ng * 4;
    float b3v[4];
#pragma unroll
    for (int j = 0; j < 4; ++j) b3v[j] = b3[jb + j];
    float acc[4][4];
#pragma unroll
    for (int n = 0; n < 4; ++n)
#pragma unroll
        for (int j = 0; j < 4; ++j) acc[n][j] = 0.f;

    // phase 2: u = in @ W3, K-chunked (8 chunks of 32)
    for (int c = 0; c < 8; ++c) {
        __syncthreads();
#pragma unroll
        for (int rep = 0; rep < 8; ++rep) {
            int idx = rep * 256 + t;
            int r = idx >> 6;       // 0..31
            int cg = idx & 63;      // 0..63 float4 cols
            float4 wv = *(const float4*)&W3[(c * 32 + r) * HID + cg * 4];
            *(float4*)&w_tile[r * 256 + cg * 4] = wv;
        }
        __syncthreads();
#pragma unroll 8
        for (int i = 0; i < 32; ++i) {
            int ii = c * 32 + i;
            float a0 = in_t[ii * STR + nb + 0];
            float a1 = in_t[ii * STR + nb + 1];
            float a2 = in_t[ii * STR + nb + 2];
            float a3 = in_t[ii * STR + nb + 3];
            float4 wv = *(const float4*)&w_tile[i * 256 + jb];
            acc[0][0] += a0 * wv.x; acc[0][1] += a0 * wv.y; acc[0][2] += a0 * wv.z; acc[0][3] += a0 * wv.w;
            acc[1][0] += a1 * wv.x; acc[1][1] += a1 * wv.y; acc[1][2] += a1 * wv.z; acc[1][3] += a1 * wv.w;
            acc[2][0] += a2 * wv.x; acc[2][1] += a2 * wv.y; acc[2][2] += a2 * wv.z; acc[2][3] += a2 * wv.w;
            acc[3][0] += a3 * wv.x; acc[3][1] += a3 * wv.y; acc[3][2] += a3 * wv.z; acc[3][3] += a3 * wv.w;
        }
    }

    // phase 3: +b3, LayerNorm stats via intra-wave butterfly (wave ng owns nodes nb..nb+3)
    float s[4], q[4];
#pragma unroll
    for (int n = 0; n < 4; ++n) {
        s[n] = 0.f; q[n] = 0.f;
#pragma unroll
        for (int j = 0; j < 4; ++j) {
            acc[n][j] += b3v[j];
            s[n] += acc[n][j];
            q[n] += acc[n][j] * acc[n][j];
        }
    }
#pragma unroll
    for (int off = 32; off > 0; off >>= 1) {
#pragma unroll
        for (int n = 0; n < 4; ++n) {
            s[n] += __shfl_xor(s[n], off, 64);
            q[n] += __shfl_xor(q[n], off, 64);
        }
    }
    float gam[4], bet[4];
#pragma unroll
    for (int j = 0; j < 4; ++j) { gam[j] = gamma[jb + j]; bet[j] = beta[jb + j]; }

    __syncthreads();   // everyone done reading in_t before overwrite
#pragma unroll
    for (int n = 0; n < 4; ++n) {
        float mu  = s[n] * (1.0f / 256.0f);
        float var = q[n] * (1.0f / 256.0f) - mu * mu;
        float rs  = rsqrtf(var + LN_EPS);
#pragma unroll
        for (int j = 0; j < 4; ++j) {
            float un = (acc[n][j] - mu) * rs * gam[j] + bet[j];
            float act = un / (1.0f + expf(-un));
            in_t[(jb + j) * STR + nb + n] = act;   // act transposed [j][node]
        }
    }
    __syncthreads();

    // phase 4: out = act @ W4 + b4, K-chunked (4 chunks of 64)
    int dg = t & 63, ng2 = t >> 6;
    int nb2 = ng2 * 4;
    float acc2[4][2];
#pragma unroll
    for (int n = 0; n < 4; ++n) { acc2[n][0] = 0.f; acc2[n][1] = 0.f; }
    for (int c2 = 0; c2 < 4; ++c2) {
        __syncthreads();
#pragma unroll
        for (int rep = 0; rep < 8; ++rep) {
            int idx = rep * 256 + t;
            int r = idx >> 5;       // 0..63
            int cg = idx & 31;      // 0..31 float4 cols
            float4 wv = *(const float4*)&W4[(c2 * 64 + r) * DIM + cg * 4];
            *(float4*)&w_tile[r * 128 + cg * 4] = wv;
        }
        __syncthreads();
#pragma unroll 8
        for (int j = 0; j < 64; ++j) {
            int jj = c2 * 64 + j;
            float a0 = in_t[jj * STR + nb2 + 0];
            float a1 = in_t[jj * STR + nb2 + 1];
            float a2 = in_t[jj * STR + nb2 + 2];
            float a3 = in_t[jj * STR + nb2 + 3];
            float w0 = w_tile[j * 128 + dg];
            float w1 = w_tile[j * 128 + 64 + dg];
            acc2[0][0] += a0 * w0; acc2[0][1] += a0 * w1;
            acc2[1][0] += a1 * w0; acc2[1][1] += a1 * w1;
            acc2[2][0] += a2 * w0; acc2[2][1] += a2 * w1;
            acc2[3][0] += a3 * w0; acc2[3][1] += a3 * w1;
        }
    }
    float b40 = b4[dg], b41 = b4[64 + dg];
#pragma unroll
    for (int n = 0; n < 4; ++n) {
        int node = n0 + nb2 + n;
        out[node * DIM + dg]      = acc2[n][0] + b40;
        out[node * DIM + 64 + dg] = acc2[n][1] + b41;
    }
}

// ---------------------------------------------------------------------------
extern "C" void kernel_launch(void* const* d_in, const int* in_sizes, int n_in,
                              void* d_out, int out_size, void* d_ws, size_t ws_size,
                              hipStream_t stream) {
    const float* x     = (const float*)d_in[0];
    const float* h     = (const float*)d_in[1];
    const int*   ei    = (const int*)d_in[2];
    const float* W1    = (const float*)d_in[4];
    const float* b1    = (const float*)d_in[5];
    const float* W2    = (const float*)d_in[6];
    const float* b2    = (const float*)d_in[7];
    const float* W3    = (const float*)d_in[8];
    const float* b3    = (const float*)d_in[9];
    const float* gamma = (const float*)d_in[10];
    const float* beta  = (const float*)d_in[11];
    const float* W4    = (const float*)d_in[12];
    const float* b4    = (const float*)d_in[13];
    float* out = (float*)d_out;
    int nE = in_sizes[2] / 2;

    char* ws = (char*)d_ws;
    float* T       = (float*)ws;  ws += (size_t)TK * DIM * 4;      // 1 MB
    int*   counts  = (int*)ws;    ws += (size_t)BN_NODES * 4;
    int*   offsets = (int*)ws;    ws += (size_t)(BN_NODES + 128) * 4;
    int*   cursor  = (int*)ws;    ws += (size_t)BN_NODES * 4;
    int*   eidx    = (int*)ws;    ws += (size_t)nE * 4;
    float* edist   = (float*)ws;  ws += (size_t)nE * 4;
    float* agg     = (float*)ws;                                   // 8 MB

    hipMemsetAsync(counts, 0, (size_t)BN_NODES * 4, stream);
    build_table<<<TK / 8, 256, 0, stream>>>(W1, b1, W2, b2, T);
    hist_kernel<<<(nE + 255) / 256, 256, 0, stream>>>(ei, counts, nE);
    scan_kernel<<<1, 256, 0, stream>>>(counts, offsets, cursor);
    scatter_kernel<<<(nE + 255) / 256, 256, 0, stream>>>(ei, x, cursor, eidx, edist, nE);
    agg_kernel<<<BN_NODES / 4, 256, 0, stream>>>(offsets, eidx, edist, h, T, agg);
    node_kernel<<<BN_NODES / NT, 256, 0, stream>>>(h, agg, W3, b3, gamma, beta, W4, b4, out);
}

// Round 2
// 288.423 us; speedup vs baseline: 1.0621x; 1.0621x over previous
//
#include <hip/hip_runtime.h>
#include <math.h>

// Problem constants (fixed by the reference)
#define BN_NODES 16384     // B*N
#define DIM 128            // D
#define HID 256            // H
#define TK 2048            // distance-table knots
#define TRANGE 32.0f
#define TSTEP (TRANGE / (float)TK)   // 1/64
#define TINV  ((float)TK / TRANGE)   // 64
#define LN_EPS 1e-5f
#define NT 16              // nodes per block in node_kernel
#define STR 17             // padded LDS stride (odd -> conflict-free transpose writes)

// ---------------------------------------------------------------------------
// K1: build distance-filter table  T[k][d] = silu(dist_k*W1+b1) @ W2 + b2
__global__ void build_table(const float* __restrict__ W1, const float* __restrict__ b1,
                            const float* __restrict__ W2, const float* __restrict__ b2,
                            float* __restrict__ T) {
    __shared__ float a[8][HID];     // silu activations, 8 KB
    __shared__ float part[8][DIM];  // partial sums from hg=1, 4 KB
    int t = threadIdx.x;
    int k0 = blockIdx.x * 8;
    float w1 = W1[t], bb = b1[t];
#pragma unroll
    for (int k = 0; k < 8; ++k) {
        float dist = (float)(k0 + k) * TSTEP;
        float z = dist * w1 + bb;
        a[k][t] = z / (1.0f + expf(-z));
    }
    __syncthreads();
    int hg = t >> 7;     // 0..1  (half of H)
    int d  = t & 127;
    float acc[8] = {0.f,0.f,0.f,0.f,0.f,0.f,0.f,0.f};
    int hbase = hg * 128;
    for (int hh = 0; hh < 128; ++hh) {
        int hidx = hbase + hh;
        float w = W2[hidx * DIM + d];
#pragma unroll
        for (int k = 0; k < 8; ++k) acc[k] += a[k][hidx] * w;
    }
    if (hg == 1) {
#pragma unroll
        for (int k = 0; k < 8; ++k) part[k][d] = acc[k];
    }
    __syncthreads();
    if (hg == 0) {
        float bd = b2[d];
#pragma unroll
        for (int k = 0; k < 8; ++k)
            T[(k0 + k) * DIM + d] = acc[k] + part[k][d] + bd;
    }
}

// ---------------------------------------------------------------------------
// K2: histogram of destination (row) nodes
__global__ void hist_kernel(const int* __restrict__ ei, int* __restrict__ counts, int nE) {
    int e = blockIdx.x * blockDim.x + threadIdx.x;
    if (e < nE) atomicAdd(&counts[ei[e]], 1);
}

// ---------------------------------------------------------------------------
// K3: single-block exclusive scan over 16384 counts -> offsets, cursor
__global__ void scan_kernel(const int* __restrict__ counts, int* __restrict__ offsets,
                            int* __restrict__ cursor) {
    __shared__ int s[256];
    int t = threadIdx.x;
    int base = t * 64;
    int sum = 0;
#pragma unroll
    for (int i = 0; i < 16; ++i) {
        int4 v = *(const int4*)&counts[base + i * 4];
        sum += v.x + v.y + v.z + v.w;
    }
    s[t] = sum;
    __syncthreads();
    for (int off = 1; off < 256; off <<= 1) {
        int v = (t >= off) ? s[t - off] : 0;
        __syncthreads();
        s[t] += v;
        __syncthreads();
    }
    int run = (t == 0) ? 0 : s[t - 1];
    for (int i = 0; i < 64; ++i) {
        int c = counts[base + i];
        offsets[base + i] = run;
        cursor[base + i]  = run;
        run += c;
    }
    if (t == 255) offsets[BN_NODES] = run;
}

// ---------------------------------------------------------------------------
// K4: scatter edges into CSR slots; compute dist per edge
__global__ void scatter_kernel(const int* __restrict__ ei, const float* __restrict__ x,
                               int* __restrict__ cursor, int* __restrict__ eidx,
                               float* __restrict__ edist, int nE) {
    int e = blockIdx.x * blockDim.x + threadIdx.x;
    if (e >= nE) return;
    int r = ei[e];
    int c = ei[nE + e];
    float dx = x[r * 3 + 0] - x[c * 3 + 0];
    float dy = x[r * 3 + 1] - x[c * 3 + 1];
    float dz = x[r * 3 + 2] - x[c * 3 + 2];
    float dist = sqrtf(dx * dx + dy * dy + dz * dz);
    int pos = atomicAdd(&cursor[r], 1);
    eidx[pos]  = c;
    edist[pos] = dist;
}

// ---------------------------------------------------------------------------
// K5 v2: per-node gather + table-interp filter + mean.
// One BLOCK per node; 4 subwaves split the edge list; cooperative index
// preload + shfl broadcast + 4-edge unroll keeps ~12 gathers in flight
// (v1 had 1 dependent gather in flight -> latency-bound at 3 GB/s).
__global__ __launch_bounds__(256) void agg_kernel(
        const int* __restrict__ offsets, const int* __restrict__ eidx,
        const float* __restrict__ edist, const float* __restrict__ h,
        const float* __restrict__ T, float* __restrict__ agg) {
    __shared__ float red[3][DIM];   // partials from subwaves 1..3
    int wave = threadIdx.x >> 6;    // 0..3
    int lane = threadIdx.x & 63;
    int node = blockIdx.x;
    int off0 = offsets[node], off1 = offsets[node + 1];
    int deg = off1 - off0;
    int q = (deg + 3) >> 2;
    int start = off0 + wave * q;
    int end = min(off1, start + q);
    float a0 = 0.f, a1 = 0.f;
    int dd = lane * 2;

    for (int base = start; base < end; base += 64) {
        int m = end - base; if (m > 64) m = 64;
        int myc = 0; float myd = 0.f;
        if (lane < m) { myc = eidx[base + lane]; myd = edist[base + lane]; }
        int i = 0;
        for (; i + 4 <= m; i += 4) {
            int   c0 = __shfl(myc, i + 0), c1 = __shfl(myc, i + 1);
            int   c2 = __shfl(myc, i + 2), c3 = __shfl(myc, i + 3);
            float u0 = __shfl(myd, i + 0) * TINV;
            float u1 = __shfl(myd, i + 1) * TINV;
            float u2 = __shfl(myd, i + 2) * TINV;
            float u3 = __shfl(myd, i + 3) * TINV;
            int k0 = min((int)u0, TK - 2); float f0 = u0 - (float)k0;
            int k1 = min((int)u1, TK - 2); float f1 = u1 - (float)k1;
            int k2 = min((int)u2, TK - 2); float f2 = u2 - (float)k2;
            int k3 = min((int)u3, TK - 2); float f3 = u3 - (float)k3;
            float2 h0 = *(const float2*)&h[c0 * DIM + dd];
            float2 h1 = *(const float2*)&h[c1 * DIM + dd];
            float2 h2 = *(const float2*)&h[c2 * DIM + dd];
            float2 h3 = *(const float2*)&h[c3 * DIM + dd];
            float2 A0 = *(const float2*)&T[k0 * DIM + dd];
            float2 B0 = *(const float2*)&T[k0 * DIM + DIM + dd];
            float2 A1 = *(const float2*)&T[k1 * DIM + dd];
            float2 B1 = *(const float2*)&T[k1 * DIM + DIM + dd];
            float2 A2 = *(const float2*)&T[k2 * DIM + dd];
            float2 B2 = *(const float2*)&T[k2 * DIM + DIM + dd];
            float2 A3 = *(const float2*)&T[k3 * DIM + dd];
            float2 B3 = *(const float2*)&T[k3 * DIM + DIM + dd];
            a0 += h0.x * (A0.x + (B0.x - A0.x) * f0);
            a1 += h0.y * (A0.y + (B0.y - A0.y) * f0);
            a0 += h1.x * (A1.x + (B1.x - A1.x) * f1);
            a1 += h1.y * (A1.y + (B1.y - A1.y) * f1);
            a0 += h2.x * (A2.x + (B2.x - A2.x) * f2);
            a1 += h2.y * (A2.y + (B2.y - A2.y) * f2);
            a0 += h3.x * (A3.x + (B3.x - A3.x) * f3);
            a1 += h3.y * (A3.y + (B3.y - A3.y) * f3);
        }
        for (; i < m; ++i) {
            int   c = __shfl(myc, i);
            float u = __shfl(myd, i) * TINV;
            int k = min((int)u, TK - 2);
            float f = u - (float)k;
            float2 hv = *(const float2*)&h[c * DIM + dd];
            float2 A  = *(const float2*)&T[k * DIM + dd];
            float2 Bv = *(const float2*)&T[k * DIM + DIM + dd];
            a0 += hv.x * (A.x + (Bv.x - A.x) * f);
            a1 += hv.y * (A.y + (Bv.y - A.y) * f);
        }
    }

    if (wave > 0) { red[wave - 1][dd] = a0; red[wave - 1][dd + 1] = a1; }
    __syncthreads();
    if (wave == 0) {
        a0 += red[0][dd]     + red[1][dd]     + red[2][dd];
        a1 += red[0][dd + 1] + red[1][dd + 1] + red[2][dd + 1];
        float inv = 1.0f / (float)max(deg, 1);
        float2 r; r.x = a0 * inv; r.y = a1 * inv;
        *(float2*)&agg[node * DIM + dd] = r;
    }
}

// ---------------------------------------------------------------------------
// K6: fused node update: u = [h,agg]@W3+b3 -> LN -> SiLU -> @W4+b4
__global__ __launch_bounds__(256) void node_kernel(
        const float* __restrict__ h, const float* __restrict__ agg,
        const float* __restrict__ W3, const float* __restrict__ b3,
        const float* __restrict__ gamma, const float* __restrict__ beta,
        const float* __restrict__ W4, const float* __restrict__ b4,
        float* __restrict__ out) {
    __shared__ float in_t[256 * STR];   // transposed [i][node], 17 KB; reused for act
    __shared__ float w_tile[32 * 256];  // 32 KB: W3 chunk [32][256] or W4 chunk [64][128]
    int t = threadIdx.x;
    int n0 = blockIdx.x * NT;

    // phase 1: load concat(h, agg) transposed into LDS
    for (int rep = 0; rep < NT; ++rep) {
        int node = n0 + rep;
        float v = (t < 128) ? h[node * DIM + t] : agg[node * DIM + (t - 128)];
        in_t[t * STR + rep] = v;
    }

    int jg = t & 63, ng = t >> 6;
    int jb = jg * 4, nb = ng * 4;
    float b3v[4];
#pragma unroll
    for (int j = 0; j < 4; ++j) b3v[j] = b3[jb + j];
    float acc[4][4];
#pragma unroll
    for (int n = 0; n < 4; ++n)
#pragma unroll
        for (int j = 0; j < 4; ++j) acc[n][j] = 0.f;

    // phase 2: u = in @ W3, K-chunked (8 chunks of 32)
    for (int c = 0; c < 8; ++c) {
        __syncthreads();
#pragma unroll
        for (int rep = 0; rep < 8; ++rep) {
            int idx = rep * 256 + t;
            int r = idx >> 6;       // 0..31
            int cg = idx & 63;      // 0..63 float4 cols
            float4 wv = *(const float4*)&W3[(c * 32 + r) * HID + cg * 4];
            *(float4*)&w_tile[r * 256 + cg * 4] = wv;
        }
        __syncthreads();
#pragma unroll 8
        for (int i = 0; i < 32; ++i) {
            int ii = c * 32 + i;
            float a0 = in_t[ii * STR + nb + 0];
            float a1 = in_t[ii * STR + nb + 1];
            float a2 = in_t[ii * STR + nb + 2];
            float a3 = in_t[ii * STR + nb + 3];
            float4 wv = *(const float4*)&w_tile[i * 256 + jb];
            acc[0][0] += a0 * wv.x; acc[0][1] += a0 * wv.y; acc[0][2] += a0 * wv.z; acc[0][3] += a0 * wv.w;
            acc[1][0] += a1 * wv.x; acc[1][1] += a1 * wv.y; acc[1][2] += a1 * wv.z; acc[1][3] += a1 * wv.w;
            acc[2][0] += a2 * wv.x; acc[2][1] += a2 * wv.y; acc[2][2] += a2 * wv.z; acc[2][3] += a2 * wv.w;
            acc[3][0] += a3 * wv.x; acc[3][1] += a3 * wv.y; acc[3][2] += a3 * wv.z; acc[3][3] += a3 * wv.w;
        }
    }

    // phase 3: +b3, LayerNorm stats via intra-wave butterfly (wave ng owns nodes nb..nb+3)
    float s[4], q[4];
#pragma unroll
    for (int n = 0; n < 4; ++n) {
        s[n] = 0.f; q[n] = 0.f;
#pragma unroll
        for (int j = 0; j < 4; ++j) {
            acc[n][j] += b3v[j];
            s[n] += acc[n][j];
            q[n] += acc[n][j] * acc[n][j];
        }
    }
#pragma unroll
    for (int off = 32; off > 0; off >>= 1) {
#pragma unroll
        for (int n = 0; n < 4; ++n) {
            s[n] += __shfl_xor(s[n], off, 64);
            q[n] += __shfl_xor(q[n], off, 64);
        }
    }
    float gam[4], bet[4];
#pragma unroll
    for (int j = 0; j < 4; ++j) { gam[j] = gamma[jb + j]; bet[j] = beta[jb + j]; }

    __syncthreads();   // everyone done reading in_t before overwrite
#pragma unroll
    for (int n = 0; n < 4; ++n) {
        float mu  = s[n] * (1.0f / 256.0f);
        float var = q[n] * (1.0f / 256.0f) - mu * mu;
        float rs  = rsqrtf(var + LN_EPS);
#pragma unroll
        for (int j = 0; j < 4; ++j) {
            float un = (acc[n][j] - mu) * rs * gam[j] + bet[j];
            float act = un / (1.0f + expf(-un));
            in_t[(jb + j) * STR + nb + n] = act;   // act transposed [j][node]
        }
    }
    __syncthreads();

    // phase 4: out = act @ W4 + b4, K-chunked (4 chunks of 64)
    int dg = t & 63, ng2 = t >> 6;
    int nb2 = ng2 * 4;
    float acc2[4][2];
#pragma unroll
    for (int n = 0; n < 4; ++n) { acc2[n][0] = 0.f; acc2[n][1] = 0.f; }
    for (int c2 = 0; c2 < 4; ++c2) {
        __syncthreads();
#pragma unroll
        for (int rep = 0; rep < 8; ++rep) {
            int idx = rep * 256 + t;
            int r = idx >> 5;       // 0..63
            int cg = idx & 31;      // 0..31 float4 cols
            float4 wv = *(const float4*)&W4[(c2 * 64 + r) * DIM + cg * 4];
            *(float4*)&w_tile[r * 128 + cg * 4] = wv;
        }
        __syncthreads();
#pragma unroll 8
        for (int j = 0; j < 64; ++j) {
            int jj = c2 * 64 + j;
            float a0 = in_t[jj * STR + nb2 + 0];
            float a1 = in_t[jj * STR + nb2 + 1];
            float a2 = in_t[jj * STR + nb2 + 2];
            float a3 = in_t[jj * STR + nb2 + 3];
            float w0 = w_tile[j * 128 + dg];
            float w1 = w_tile[j * 128 + 64 + dg];
            acc2[0][0] += a0 * w0; acc2[0][1] += a0 * w1;
            acc2[1][0] += a1 * w0; acc2[1][1] += a1 * w1;
            acc2[2][0] += a2 * w0; acc2[2][1] += a2 * w1;
            acc2[3][0] += a3 * w0; acc2[3][1] += a3 * w1;
        }
    }
    float b40 = b4[dg], b41 = b4[64 + dg];
#pragma unroll
    for (int n = 0; n < 4; ++n) {
        int node = n0 + nb2 + n;
        out[node * DIM + dg]      = acc2[n][0] + b40;
        out[node * DIM + 64 + dg] = acc2[n][1] + b41;
    }
}

// ---------------------------------------------------------------------------
extern "C" void kernel_launch(void* const* d_in, const int* in_sizes, int n_in,
                              void* d_out, int out_size, void* d_ws, size_t ws_size,
                              hipStream_t stream) {
    const float* x     = (const float*)d_in[0];
    const float* h     = (const float*)d_in[1];
    const int*   ei    = (const int*)d_in[2];
    const float* W1    = (const float*)d_in[4];
    const float* b1    = (const float*)d_in[5];
    const float* W2    = (const float*)d_in[6];
    const float* b2    = (const float*)d_in[7];
    const float* W3    = (const float*)d_in[8];
    const float* b3    = (const float*)d_in[9];
    const float* gamma = (const float*)d_in[10];
    const float* beta  = (const float*)d_in[11];
    const float* W4    = (const float*)d_in[12];
    const float* b4    = (const float*)d_in[13];
    float* out = (float*)d_out;
    int nE = in_sizes[2] / 2;

    char* ws = (char*)d_ws;
    float* T       = (float*)ws;  ws += (size_t)TK * DIM * 4;      // 1 MB
    int*   counts  = (int*)ws;    ws += (size_t)BN_NODES * 4;
    int*   offsets = (int*)ws;    ws += (size_t)(BN_NODES + 128) * 4;
    int*   cursor  = (int*)ws;    ws += (size_t)BN_NODES * 4;
    int*   eidx    = (int*)ws;    ws += (size_t)nE * 4;
    float* edist   = (float*)ws;  ws += (size_t)nE * 4;
    float* agg     = (float*)ws;                                   // 8 MB

    hipMemsetAsync(counts, 0, (size_t)BN_NODES * 4, stream);
    build_table<<<TK / 8, 256, 0, stream>>>(W1, b1, W2, b2, T);
    hist_kernel<<<(nE + 255) / 256, 256, 0, stream>>>(ei, counts, nE);
    scan_kernel<<<1, 256, 0, stream>>>(counts, offsets, cursor);
    scatter_kernel<<<(nE + 255) / 256, 256, 0, stream>>>(ei, x, cursor, eidx, edist, nE);
    agg_kernel<<<BN_NODES, 256, 0, stream>>>(offsets, eidx, edist, h, T, agg);
    node_kernel<<<BN_NODES / NT, 256, 0, stream>>>(h, agg, W3, b3, gamma, beta, W4, b4, out);
}

// Round 3
// 217.258 us; speedup vs baseline: 1.4100x; 1.3276x over previous
//
#include <hip/hip_runtime.h>
#include <math.h>

// Problem constants (fixed by the reference)
#define BN_NODES 16384     // B*N
#define DIM 128            // D
#define HID 256            // H
#define TK 2048            // distance-table knots
#define TRANGE 32.0f
#define TSTEP (TRANGE / (float)TK)   // 1/64
#define TINV  ((float)TK / TRANGE)   // 64
#define LN_EPS 1e-5f

typedef __attribute__((ext_vector_type(8))) short bf16x8;
typedef __attribute__((ext_vector_type(4))) float f32x4;
typedef __attribute__((ext_vector_type(8))) unsigned short ushort8v;

__device__ __forceinline__ unsigned short f2bf(float f) {
    unsigned int u = __float_as_uint(f);
    u += 0x7fffu + ((u >> 16) & 1u);           // RNE
    return (unsigned short)(u >> 16);
}
__device__ __forceinline__ float bf2f(unsigned short s) {
    return __uint_as_float(((unsigned int)s) << 16);
}

// ---------------------------------------------------------------------------
// K1 "prep" (fused): blocks 0..255 build bf16 filter table Tb[2048][128];
// 256..319 transpose W3 -> w3t[n][k] bf16; 320..351 transpose W4 -> w4t[n][k];
// 352..1375 convert h -> xb[:, 0:128] bf16; 1376.. histogram of row nodes.
__global__ __launch_bounds__(256) void prep_kernel(
        const float* __restrict__ W1, const float* __restrict__ b1,
        const float* __restrict__ W2, const float* __restrict__ b2,
        const float* __restrict__ W3, const float* __restrict__ W4,
        const float* __restrict__ h, const int* __restrict__ ei,
        unsigned short* __restrict__ Tb, unsigned short* __restrict__ w3t,
        unsigned short* __restrict__ w4t, unsigned short* __restrict__ xb,
        int* __restrict__ counts, int nE) {
    __shared__ float smem[8 * 256 + 8 * 128];   // 12 KB, role-dependent
    int bid = blockIdx.x, t = threadIdx.x;
    if (bid < 256) {
        // --- distance-filter table: Tb[k][d] = silu(dist*W1+b1)@W2 + b2
        float* a    = smem;          // [8][256]
        float* part = smem + 2048;   // [8][128]
        int k0 = bid * 8;
        float w1 = W1[t], bb = b1[t];
#pragma unroll
        for (int k = 0; k < 8; ++k) {
            float dist = (float)(k0 + k) * TSTEP;
            float z = dist * w1 + bb;
            a[k * 256 + t] = z / (1.0f + expf(-z));
        }
        __syncthreads();
        int hg = t >> 7, d = t & 127;
        float acc[8] = {0.f,0.f,0.f,0.f,0.f,0.f,0.f,0.f};
        for (int hh = 0; hh < 128; ++hh) {
            int hidx = hg * 128 + hh;
            float w = W2[hidx * DIM + d];
#pragma unroll
            for (int k = 0; k < 8; ++k) acc[k] += a[k * 256 + hidx] * w;
        }
        if (hg == 1) {
#pragma unroll
            for (int k = 0; k < 8; ++k) part[k * 128 + d] = acc[k];
        }
        __syncthreads();
        if (hg == 0) {
            float bd = b2[d];
#pragma unroll
            for (int k = 0; k < 8; ++k)
                Tb[(k0 + k) * DIM + d] = f2bf(acc[k] + part[k * 128 + d] + bd);
        }
    } else if (bid < 320) {
        // --- W3 [256k][256n] -> w3t [256n][256k] bf16, 32x32 tiles
        float* s = smem;   // [32][33]
        int tid = bid - 256, tr = tid >> 3, tc = tid & 7;
        int lr = t >> 5, lc = t & 31;
#pragma unroll
        for (int rep = 0; rep < 4; ++rep) {
            int k = tr * 32 + rep * 8 + lr, n = tc * 32 + lc;
            s[lc * 33 + rep * 8 + lr] = W3[k * 256 + n];
        }
        __syncthreads();
#pragma unroll
        for (int rep = 0; rep < 4; ++rep) {
            int n = tc * 32 + rep * 8 + lr, k = tr * 32 + lc;
            w3t[n * 256 + k] = f2bf(s[(rep * 8 + lr) * 33 + lc]);
        }
    } else if (bid < 352) {
        // --- W4 [256k][128n] -> w4t [128n][256k] bf16
        float* s = smem;
        int tid = bid - 320, tr = tid >> 2, tc = tid & 3;
        int lr = t >> 5, lc = t & 31;
#pragma unroll
        for (int rep = 0; rep < 4; ++rep) {
            int k = tr * 32 + rep * 8 + lr, n = tc * 32 + lc;
            s[lc * 33 + rep * 8 + lr] = W4[k * 128 + n];
        }
        __syncthreads();
#pragma unroll
        for (int rep = 0; rep < 4; ++rep) {
            int n = tc * 32 + rep * 8 + lr, k = tr * 32 + lc;
            w4t[n * 256 + k] = f2bf(s[(rep * 8 + lr) * 33 + lc]);
        }
    } else if (bid < 1376) {
        // --- h fp32 -> xb[node][0:128] bf16 (8 elems/thread, same row)
        int i0 = (bid - 352) * 2048 + t * 8;
        float4 v0 = *(const float4*)&h[i0];
        float4 v1 = *(const float4*)&h[i0 + 4];
        int node = i0 >> 7, col = i0 & 127;
        ushort8v o;
        o[0] = f2bf(v0.x); o[1] = f2bf(v0.y); o[2] = f2bf(v0.z); o[3] = f2bf(v0.w);
        o[4] = f2bf(v1.x); o[5] = f2bf(v1.y); o[6] = f2bf(v1.z); o[7] = f2bf(v1.w);
        *(ushort8v*)&xb[node * 256 + col] = o;
    } else {
        // --- histogram of destination nodes
        int e = (bid - 1376) * 256 + t;
        if (e < nE) atomicAdd(&counts[ei[e]], 1);
    }
}

// ---------------------------------------------------------------------------
// K2: exclusive scan over 16384 counts (1024 threads, 16 each)
__global__ void scan_kernel(const int* __restrict__ counts, int* __restrict__ offsets,
                            int* __restrict__ cursor) {
    __shared__ int s[1024];
    int t = threadIdx.x;
    int base = t * 16;
    int sum = 0;
#pragma unroll
    for (int i = 0; i < 4; ++i) {
        int4 v = *(const int4*)&counts[base + i * 4];
        sum += v.x + v.y + v.z + v.w;
    }
    s[t] = sum;
    __syncthreads();
    for (int off = 1; off < 1024; off <<= 1) {
        int v = (t >= off) ? s[t - off] : 0;
        __syncthreads();
        s[t] += v;
        __syncthreads();
    }
    int run = (t == 0) ? 0 : s[t - 1];
    for (int i = 0; i < 16; ++i) {
        int c = counts[base + i];
        offsets[base + i] = run;
        cursor[base + i]  = run;
        run += c;
    }
    if (t == 1023) offsets[BN_NODES] = run;
}

// ---------------------------------------------------------------------------
// K3: scatter edges into CSR slots; compute dist per edge
__global__ void scatter_kernel(const int* __restrict__ ei, const float* __restrict__ x,
                               int* __restrict__ cursor, int* __restrict__ eidx,
                               float* __restrict__ edist, int nE) {
    int e = blockIdx.x * blockDim.x + threadIdx.x;
    if (e >= nE) return;
    int r = ei[e];
    int c = ei[nE + e];
    float dx = x[r * 3 + 0] - x[c * 3 + 0];
    float dy = x[r * 3 + 1] - x[c * 3 + 1];
    float dz = x[r * 3 + 2] - x[c * 3 + 2];
    float dist = sqrtf(dx * dx + dy * dy + dz * dz);
    int pos = atomicAdd(&cursor[r], 1);
    eidx[pos]  = c;
    edist[pos] = dist;
}

// ---------------------------------------------------------------------------
// K4: per-node gather (bf16 xb rows + bf16 table) + mean -> xb[:,128:256] bf16.
// One block per node; 4 subwaves split edges; shfl broadcast + 4-edge unroll.
__global__ __launch_bounds__(256) void agg_kernel(
        const int* __restrict__ offsets, const int* __restrict__ eidx,
        const float* __restrict__ edist, const unsigned short* __restrict__ Tb,
        unsigned short* __restrict__ xb) {
    __shared__ float red[3][DIM];
    int wave = threadIdx.x >> 6;
    int lane = threadIdx.x & 63;
    int node = blockIdx.x;
    int off0 = offsets[node], off1 = offsets[node + 1];
    int deg = off1 - off0;
    int qd = (deg + 3) >> 2;
    int start = off0 + wave * qd;
    int end = min(off1, start + qd);
    float a0 = 0.f, a1 = 0.f;
    int dd = lane * 2;

    for (int base = start; base < end; base += 64) {
        int m = end - base; if (m > 64) m = 64;
        int myc = 0; float myd = 0.f;
        if (lane < m) { myc = eidx[base + lane]; myd = edist[base + lane]; }
        int i = 0;
        for (; i + 4 <= m; i += 4) {
            int   c0 = __shfl(myc, i + 0), c1 = __shfl(myc, i + 1);
            int   c2 = __shfl(myc, i + 2), c3 = __shfl(myc, i + 3);
            float u0 = __shfl(myd, i + 0) * TINV;
            float u1 = __shfl(myd, i + 1) * TINV;
            float u2 = __shfl(myd, i + 2) * TINV;
            float u3 = __shfl(myd, i + 3) * TINV;
            int k0 = min((int)u0, TK - 2); float f0 = u0 - (float)k0;
            int k1 = min((int)u1, TK - 2); float f1 = u1 - (float)k1;
            int k2 = min((int)u2, TK - 2); float f2 = u2 - (float)k2;
            int k3 = min((int)u3, TK - 2); float f3 = u3 - (float)k3;
            unsigned int h0 = *(const unsigned int*)&xb[c0 * 256 + dd];
            unsigned int h1 = *(const unsigned int*)&xb[c1 * 256 + dd];
            unsigned int h2 = *(const unsigned int*)&xb[c2 * 256 + dd];
            unsigned int h3 = *(const unsigned int*)&xb[c3 * 256 + dd];
            unsigned int A0 = *(const unsigned int*)&Tb[k0 * DIM + dd];
            unsigned int B0 = *(const unsigned int*)&Tb[k0 * DIM + DIM + dd];
            unsigned int A1 = *(const unsigned int*)&Tb[k1 * DIM + dd];
            unsigned int B1 = *(const unsigned int*)&Tb[k1 * DIM + DIM + dd];
            unsigned int A2 = *(const unsigned int*)&Tb[k2 * DIM + dd];
            unsigned int B2 = *(const unsigned int*)&Tb[k2 * DIM + DIM + dd];
            unsigned int A3 = *(const unsigned int*)&Tb[k3 * DIM + dd];
            unsigned int B3 = *(const unsigned int*)&Tb[k3 * DIM + DIM + dd];
            float ax, bx, ay, by;
            ax = bf2f((unsigned short)A0); bx = bf2f((unsigned short)(A0 >> 16));
            ay = bf2f((unsigned short)B0); by = bf2f((unsigned short)(B0 >> 16));
            a0 += bf2f((unsigned short)h0)         * (ax + (ay - ax) * f0);
            a1 += bf2f((unsigned short)(h0 >> 16)) * (bx + (by - bx) * f0);
            ax = bf2f((unsigned short)A1); bx = bf2f((unsigned short)(A1 >> 16));
            ay = bf2f((unsigned short)B1); by = bf2f((unsigned short)(B1 >> 16));
            a0 += bf2f((unsigned short)h1)         * (ax + (ay - ax) * f1);
            a1 += bf2f((unsigned short)(h1 >> 16)) * (bx + (by - bx) * f1);
            ax = bf2f((unsigned short)A2); bx = bf2f((unsigned short)(A2 >> 16));
            ay = bf2f((unsigned short)B2); by = bf2f((unsigned short)(B2 >> 16));
            a0 += bf2f((unsigned short)h2)         * (ax + (ay - ax) * f2);
            a1 += bf2f((unsigned short)(h2 >> 16)) * (bx + (by - bx) * f2);
            ax = bf2f((unsigned short)A3); bx = bf2f((unsigned short)(A3 >> 16));
            ay = bf2f((unsigned short)B3); by = bf2f((unsigned short)(B3 >> 16));
            a0 += bf2f((unsigned short)h3)         * (ax + (ay - ax) * f3);
            a1 += bf2f((unsigned short)(h3 >> 16)) * (bx + (by - bx) * f3);
        }
        for (; i < m; ++i) {
            int   c = __shfl(myc, i);
            float u = __shfl(myd, i) * TINV;
            int k = min((int)u, TK - 2);
            float f = u - (float)k;
            unsigned int hv = *(const unsigned int*)&xb[c * 256 + dd];
            unsigned int Av = *(const unsigned int*)&Tb[k * DIM + dd];
            unsigned int Bv = *(const unsigned int*)&Tb[k * DIM + DIM + dd];
            float ax = bf2f((unsigned short)Av), bx = bf2f((unsigned short)(Av >> 16));
            float ay = bf2f((unsigned short)Bv), by = bf2f((unsigned short)(Bv >> 16));
            a0 += bf2f((unsigned short)hv)         * (ax + (ay - ax) * f);
            a1 += bf2f((unsigned short)(hv >> 16)) * (bx + (by - bx) * f);
        }
    }

    if (wave > 0) { red[wave - 1][dd] = a0; red[wave - 1][dd + 1] = a1; }
    __syncthreads();
    if (wave == 0) {
        a0 += red[0][dd]     + red[1][dd]     + red[2][dd];
        a1 += red[0][dd + 1] + red[1][dd + 1] + red[2][dd + 1];
        float inv = 1.0f / (float)max(deg, 1);
        unsigned int packed = (unsigned int)f2bf(a0 * inv)
                            | ((unsigned int)f2bf(a1 * inv) << 16);
        *(unsigned int*)&xb[node * 256 + 128 + dd] = packed;
    }
}

// ---------------------------------------------------------------------------
// K5: fused node update via MFMA bf16.
// Block = 64 nodes, 4 waves. GEMM1: U[64,256] = xb[64,256] @ W3; waves split
// the 256 output cols (64 each). A/B fragments loaded directly from global
// (L2-hot). LN stats: intra-quad shfl_xor + cross-wave LDS partials. Act ->
// bf16 in LDS (A-layout), GEMM2: out[64,128] = act @ W4 (waves split 32 cols).
// MFMA layouts (m89-verified): A[m=lane&15][k=(lane>>4)*8+j];
// C/D: col=lane&15, row=(lane>>4)*4+reg.
__global__ __launch_bounds__(256) void node_kernel(
        const unsigned short* __restrict__ xb, const unsigned short* __restrict__ w3t,
        const float* __restrict__ b3, const float* __restrict__ gamma,
        const float* __restrict__ beta, const unsigned short* __restrict__ w4t,
        const float* __restrict__ b4, float* __restrict__ out) {
    __shared__ __align__(16) unsigned short a_lds[64][264];  // act, bf16, 33 KB
    __shared__ float part_s[4][64];
    __shared__ float part_q[4][64];
    int t = threadIdx.x;
    int wv = t >> 6, lane = t & 63;
    int q = lane >> 4, l15 = lane & 15;
    int n0 = blockIdx.x * 64;

    // ---- GEMM1: acc[mt][nt] = X[64x256] @ W3 (this wave's 64-col slice)
    f32x4 acc[4][4];
#pragma unroll
    for (int mt = 0; mt < 4; ++mt)
#pragma unroll
        for (int nt = 0; nt < 4; ++nt)
            acc[mt][nt] = (f32x4){0.f, 0.f, 0.f, 0.f};

    for (int kc = 0; kc < 8; ++kc) {
        bf16x8 a[4];
#pragma unroll
        for (int mt = 0; mt < 4; ++mt)
            a[mt] = *(const bf16x8*)&xb[(n0 + mt * 16 + l15) * 256 + kc * 32 + q * 8];
#pragma unroll
        for (int nt = 0; nt < 4; ++nt) {
            bf16x8 b = *(const bf16x8*)&w3t[(wv * 64 + nt * 16 + l15) * 256 + kc * 32 + q * 8];
#pragma unroll
            for (int mt = 0; mt < 4; ++mt)
                acc[mt][nt] = __builtin_amdgcn_mfma_f32_16x16x32_bf16(a[mt], b, acc[mt][nt], 0, 0, 0);
        }
    }

    // ---- bias + LN stats
    float b3v[4], gv[4], bv[4];
#pragma unroll
    for (int nt = 0; nt < 4; ++nt) {
        int col = wv * 64 + nt * 16 + l15;
        b3v[nt] = b3[col]; gv[nt] = gamma[col]; bv[nt] = beta[col];
    }
    float s[4][4], ss[4][4];   // [mt][reg]
#pragma unroll
    for (int mt = 0; mt < 4; ++mt)
#pragma unroll
        for (int reg = 0; reg < 4; ++reg) {
            float su = 0.f, sq = 0.f;
#pragma unroll
            for (int nt = 0; nt < 4; ++nt) {
                float v = acc[mt][nt][reg] + b3v[nt];
                acc[mt][nt][reg] = v;
                su += v; sq += v * v;
            }
            s[mt][reg] = su; ss[mt][reg] = sq;
        }
#pragma unroll
    for (int off = 1; off < 16; off <<= 1) {
#pragma unroll
        for (int mt = 0; mt < 4; ++mt)
#pragma unroll
            for (int reg = 0; reg < 4; ++reg) {
                s[mt][reg]  += __shfl_xor(s[mt][reg],  off, 64);
                ss[mt][reg] += __shfl_xor(ss[mt][reg], off, 64);
            }
    }
    if (l15 == 0) {
#pragma unroll
        for (int mt = 0; mt < 4; ++mt)
#pragma unroll
            for (int reg = 0; reg < 4; ++reg) {
                int r = mt * 16 + q * 4 + reg;
                part_s[wv][r] = s[mt][reg];
                part_q[wv][r] = ss[mt][reg];
            }
    }
    __syncthreads();

    // ---- LN + SiLU -> bf16 act in LDS (A-operand layout [m][k])
#pragma unroll
    for (int mt = 0; mt < 4; ++mt)
#pragma unroll
        for (int reg = 0; reg < 4; ++reg) {
            int r = mt * 16 + q * 4 + reg;
            float st = part_s[0][r] + part_s[1][r] + part_s[2][r] + part_s[3][r];
            float qt = part_q[0][r] + part_q[1][r] + part_q[2][r] + part_q[3][r];
            float mu = st * (1.0f / 256.0f);
            float var = qt * (1.0f / 256.0f) - mu * mu;
            float rs = rsqrtf(var + LN_EPS);
#pragma unroll
            for (int nt = 0; nt < 4; ++nt) {
                float un = (acc[mt][nt][reg] - mu) * rs * gv[nt] + bv[nt];
                float act = un / (1.0f + expf(-un));
                a_lds[r][wv * 64 + nt * 16 + l15] = f2bf(act);
            }
        }
    __syncthreads();

    // ---- GEMM2: out[64,128] = act @ W4; this wave: cols wv*32 .. wv*32+31
    f32x4 acc2[4][2];
#pragma unroll
    for (int mt = 0; mt < 4; ++mt)
#pragma unroll
        for (int nt = 0; nt < 2; ++nt)
            acc2[mt][nt] = (f32x4){0.f, 0.f, 0.f, 0.f};
    for (int kc = 0; kc < 8; ++kc) {
        bf16x8 a[4];
#pragma unroll
        for (int mt = 0; mt < 4; ++mt)
            a[mt] = *(const bf16x8*)&a_lds[mt * 16 + l15][kc * 32 + q * 8];
#pragma unroll
        for (int nt = 0; nt < 2; ++nt) {
            bf16x8 b = *(const bf16x8*)&w4t[(wv * 32 + nt * 16 + l15) * 256 + kc * 32 + q * 8];
#pragma unroll
            for (int mt = 0; mt < 4; ++mt)
                acc2[mt][nt] = __builtin_amdgcn_mfma_f32_16x16x32_bf16(a[mt], b, acc2[mt][nt], 0, 0, 0);
        }
    }
    float b4v[2];
#pragma unroll
    for (int nt = 0; nt < 2; ++nt) b4v[nt] = b4[wv * 32 + nt * 16 + l15];
#pragma unroll
    for (int mt = 0; mt < 4; ++mt)
#pragma unroll
        for (int nt = 0; nt < 2; ++nt)
#pragma unroll
            for (int reg = 0; reg < 4; ++reg) {
                int node = n0 + mt * 16 + q * 4 + reg;
                out[node * DIM + wv * 32 + nt * 16 + l15] = acc2[mt][nt][reg] + b4v[nt];
            }
}

// ---------------------------------------------------------------------------
extern "C" void kernel_launch(void* const* d_in, const int* in_sizes, int n_in,
                              void* d_out, int out_size, void* d_ws, size_t ws_size,
                              hipStream_t stream) {
    const float* x     = (const float*)d_in[0];
    const float* h     = (const float*)d_in[1];
    const int*   ei    = (const int*)d_in[2];
    const float* W1    = (const float*)d_in[4];
    const float* b1    = (const float*)d_in[5];
    const float* W2    = (const float*)d_in[6];
    const float* b2    = (const float*)d_in[7];
    const float* W3    = (const float*)d_in[8];
    const float* b3    = (const float*)d_in[9];
    const float* gamma = (const float*)d_in[10];
    const float* beta  = (const float*)d_in[11];
    const float* W4    = (const float*)d_in[12];
    const float* b4    = (const float*)d_in[13];
    float* out = (float*)d_out;
    int nE = in_sizes[2] / 2;

    char* ws = (char*)d_ws;
    unsigned short* Tb  = (unsigned short*)ws; ws += (size_t)TK * DIM * 2;       // 512 KB
    unsigned short* w3t = (unsigned short*)ws; ws += (size_t)HID * HID * 2;      // 128 KB
    unsigned short* w4t = (unsigned short*)ws; ws += (size_t)DIM * HID * 2;      // 64 KB
    unsigned short* xb  = (unsigned short*)ws; ws += (size_t)BN_NODES * 256 * 2; // 8 MB
    int*   counts  = (int*)ws;   ws += (size_t)BN_NODES * 4;
    int*   offsets = (int*)ws;   ws += (size_t)(BN_NODES + 128) * 4;
    int*   cursor  = (int*)ws;   ws += (size_t)BN_NODES * 4;
    int*   eidx    = (int*)ws;   ws += (size_t)nE * 4;
    float* edist   = (float*)ws; ws += (size_t)nE * 4;

    int histBlocks = (nE + 255) / 256;
    hipMemsetAsync(counts, 0, (size_t)BN_NODES * 4, stream);
    prep_kernel<<<1376 + histBlocks, 256, 0, stream>>>(W1, b1, W2, b2, W3, W4, h, ei,
                                                       Tb, w3t, w4t, xb, counts, nE);
    scan_kernel<<<1, 1024, 0, stream>>>(counts, offsets, cursor);
    scatter_kernel<<<histBlocks, 256, 0, stream>>>(ei, x, cursor, eidx, edist, nE);
    agg_kernel<<<BN_NODES, 256, 0, stream>>>(offsets, eidx, edist, Tb, xb);
    node_kernel<<<BN_NODES / 64, 256, 0, stream>>>(xb, w3t, b3, gamma, beta, w4t, b4, out);
}

// Round 4
// 189.113 us; speedup vs baseline: 1.6198x; 1.1488x over previous
//
#include <hip/hip_runtime.h>
#include <math.h>

// Problem constants (fixed by the reference)
#define BN_NODES 16384     // B*N
#define DIM 128            // D
#define HID 256            // H
#define TK 2048            // distance-table knots
#define TRANGE 32.0f
#define TSTEP (TRANGE / (float)TK)   // 1/64
#define TINV  ((float)TK / TRANGE)   // 64
#define LN_EPS 1e-5f
#define EPB 4096           // edges per block in binA

typedef __attribute__((ext_vector_type(8))) short bf16x8;
typedef __attribute__((ext_vector_type(4))) float f32x4;
typedef __attribute__((ext_vector_type(8))) unsigned short ushort8v;

__device__ __forceinline__ unsigned short f2bf(float f) {
    unsigned int u = __float_as_uint(f);
    u += 0x7fffu + ((u >> 16) & 1u);           // RNE
    return (unsigned short)(u >> 16);
}
__device__ __forceinline__ float bf2f(unsigned short s) {
    return __uint_as_float(((unsigned int)s) << 16);
}

// ---------------------------------------------------------------------------
// K1 "prep" (fused): blocks 0..255 build bf16 filter table Tb[2048][128];
// 256..319 transpose W3 -> w3t[n][k] bf16; 320..351 transpose W4 -> w4t[n][k];
// 352..1375 convert h -> xb[:, 0:128] bf16; 1376.. histogram of row nodes.
__global__ __launch_bounds__(256) void prep_kernel(
        const float* __restrict__ W1, const float* __restrict__ b1,
        const float* __restrict__ W2, const float* __restrict__ b2,
        const float* __restrict__ W3, const float* __restrict__ W4,
        const float* __restrict__ h, const int* __restrict__ ei,
        unsigned short* __restrict__ Tb, unsigned short* __restrict__ w3t,
        unsigned short* __restrict__ w4t, unsigned short* __restrict__ xb,
        int* __restrict__ counts, int nE) {
    __shared__ float smem[8 * 256 + 8 * 128];   // 12 KB, role-dependent
    int bid = blockIdx.x, t = threadIdx.x;
    if (bid < 256) {
        // --- distance-filter table: Tb[k][d] = silu(dist*W1+b1)@W2 + b2
        float* a    = smem;          // [8][256]
        float* part = smem + 2048;   // [8][128]
        int k0 = bid * 8;
        float w1 = W1[t], bb = b1[t];
#pragma unroll
        for (int k = 0; k < 8; ++k) {
            float dist = (float)(k0 + k) * TSTEP;
            float z = dist * w1 + bb;
            a[k * 256 + t] = z / (1.0f + expf(-z));
        }
        __syncthreads();
        int hg = t >> 7, d = t & 127;
        float acc[8] = {0.f,0.f,0.f,0.f,0.f,0.f,0.f,0.f};
        for (int hh = 0; hh < 128; ++hh) {
            int hidx = hg * 128 + hh;
            float w = W2[hidx * DIM + d];
#pragma unroll
            for (int k = 0; k < 8; ++k) acc[k] += a[k * 256 + hidx] * w;
        }
        if (hg == 1) {
#pragma unroll
            for (int k = 0; k < 8; ++k) part[k * 128 + d] = acc[k];
        }
        __syncthreads();
        if (hg == 0) {
            float bd = b2[d];
#pragma unroll
            for (int k = 0; k < 8; ++k)
                Tb[(k0 + k) * DIM + d] = f2bf(acc[k] + part[k * 128 + d] + bd);
        }
    } else if (bid < 320) {
        // --- W3 [256k][256n] -> w3t [256n][256k] bf16, 32x32 tiles
        float* s = smem;   // [32][33]
        int tid = bid - 256, tr = tid >> 3, tc = tid & 7;
        int lr = t >> 5, lc = t & 31;
#pragma unroll
        for (int rep = 0; rep < 4; ++rep) {
            int k = tr * 32 + rep * 8 + lr, n = tc * 32 + lc;
            s[lc * 33 + rep * 8 + lr] = W3[k * 256 + n];
        }
        __syncthreads();
#pragma unroll
        for (int rep = 0; rep < 4; ++rep) {
            int n = tc * 32 + rep * 8 + lr, k = tr * 32 + lc;
            w3t[n * 256 + k] = f2bf(s[(rep * 8 + lr) * 33 + lc]);
        }
    } else if (bid < 352) {
        // --- W4 [256k][128n] -> w4t [128n][256k] bf16
        float* s = smem;
        int tid = bid - 320, tr = tid >> 2, tc = tid & 3;
        int lr = t >> 5, lc = t & 31;
#pragma unroll
        for (int rep = 0; rep < 4; ++rep) {
            int k = tr * 32 + rep * 8 + lr, n = tc * 32 + lc;
            s[lc * 33 + rep * 8 + lr] = W4[k * 128 + n];
        }
        __syncthreads();
#pragma unroll
        for (int rep = 0; rep < 4; ++rep) {
            int n = tc * 32 + rep * 8 + lr, k = tr * 32 + lc;
            w4t[n * 256 + k] = f2bf(s[(rep * 8 + lr) * 33 + lc]);
        }
    } else if (bid < 1376) {
        // --- h fp32 -> xb[node][0:128] bf16 (8 elems/thread, same row)
        int i0 = (bid - 352) * 2048 + t * 8;
        float4 v0 = *(const float4*)&h[i0];
        float4 v1 = *(const float4*)&h[i0 + 4];
        int node = i0 >> 7, col = i0 & 127;
        ushort8v o;
        o[0] = f2bf(v0.x); o[1] = f2bf(v0.y); o[2] = f2bf(v0.z); o[3] = f2bf(v0.w);
        o[4] = f2bf(v1.x); o[5] = f2bf(v1.y); o[6] = f2bf(v1.z); o[7] = f2bf(v1.w);
        *(ushort8v*)&xb[node * 256 + col] = o;
    } else {
        // --- histogram of destination nodes
        int e = (bid - 1376) * 256 + t;
        if (e < nE) atomicAdd(&counts[ei[e]], 1);
    }
}

// ---------------------------------------------------------------------------
// K2: exclusive scan over 16384 counts (1024 threads, 16 each) + bin cursors
__global__ void scan_kernel(const int* __restrict__ counts, int* __restrict__ offsets,
                            int* __restrict__ bin_cursor) {
    __shared__ int s[1024];
    int t = threadIdx.x;
    int base = t * 16;
    int sum = 0;
#pragma unroll
    for (int i = 0; i < 4; ++i) {
        int4 v = *(const int4*)&counts[base + i * 4];
        sum += v.x + v.y + v.z + v.w;
    }
    s[t] = sum;
    __syncthreads();
    for (int off = 1; off < 1024; off <<= 1) {
        int v = (t >= off) ? s[t - off] : 0;
        __syncthreads();
        s[t] += v;
        __syncthreads();
    }
    int run = (t == 0) ? 0 : s[t - 1];
    for (int i = 0; i < 16; ++i) {
        int c = counts[base + i];
        offsets[base + i] = run;
        run += c;
    }
    if (t == 1023) offsets[BN_NODES] = run;
    __syncthreads();
    if (t < 256) bin_cursor[t] = offsets[t * 64];
}

// ---------------------------------------------------------------------------
// K3a: bin scatter phase A — LDS counting-sort 4096-edge chunks into 256 bins
// (bin = row>>6), burst-write 4B codes (row<<16|col) to per-bin staging.
// Replaces the random-scatter kernel whose 4B stores on random 64B lines,
// dirtied from all 8 non-coherent XCD L2s, caused 13x write amplification
// (WRITE_SIZE 55 MB for a 4.2 MB payload).
__global__ __launch_bounds__(256) void binA_kernel(
        const int* __restrict__ ei, int* __restrict__ bin_cursor,
        unsigned int* __restrict__ staging, int nE) {
    __shared__ int cnt[256];
    __shared__ int pre[256];
    __shared__ int gbase[256];
    __shared__ unsigned int rec[EPB];   // 16 KB
    int t = threadIdx.x;
    int e0 = blockIdx.x * EPB;
    int m = min(EPB, nE - e0);
    cnt[t] = 0;
    __syncthreads();
    unsigned int code[16];
    int rk[16], bn[16];
#pragma unroll
    for (int j = 0; j < 16; ++j) {
        int idx = j * 256 + t;
        rk[j] = -1; bn[j] = 0; code[j] = 0;
        if (idx < m) {
            int e = e0 + idx;
            int r = ei[e], c = ei[nE + e];
            code[j] = ((unsigned int)r << 16) | (unsigned int)c;
            bn[j] = r >> 6;
            rk[j] = atomicAdd(&cnt[bn[j]], 1);
        }
    }
    __syncthreads();
    // exclusive scan of cnt -> pre
    int v = cnt[t];
    pre[t] = v;
    __syncthreads();
    for (int off = 1; off < 256; off <<= 1) {
        int add = (t >= off) ? pre[t - off] : 0;
        __syncthreads();
        pre[t] += add;
        __syncthreads();
    }
    int excl = pre[t] - v;
    __syncthreads();
    pre[t] = excl;
    gbase[t] = atomicAdd(&bin_cursor[t], v);
    __syncthreads();
#pragma unroll
    for (int j = 0; j < 16; ++j)
        if (rk[j] >= 0) rec[pre[bn[j]] + rk[j]] = code[j];
    __syncthreads();
    for (int i = t; i < m; i += 256) {
        unsigned int cd = rec[i];
        int b = cd >> 22;               // row >> 6
        staging[gbase[b] + (i - pre[b])] = cd;
    }
}

// ---------------------------------------------------------------------------
// K3b: phase B — one block per bin; read staging slice sequentially, compute
// dist (x is L2/L3-resident), scatter (col,dist) into final CSR positions via
// LDS cursors. All writes land in this block's 16 KB window -> lines fill
// completely in one XCD's L2 -> writeback = payload.
__global__ __launch_bounds__(256) void binB_kernel(
        const unsigned int* __restrict__ staging, const float* __restrict__ x,
        const int* __restrict__ offsets, uint2* __restrict__ erec) {
    __shared__ int cur[64];
    int t = threadIdx.x;
    int bin = blockIdx.x;
    int s0 = offsets[bin * 64];
    int s1 = offsets[bin * 64 + 64];
    if (t < 64) cur[t] = offsets[bin * 64 + t];
    __syncthreads();
    for (int i = s0 + t; i < s1; i += 256) {
        unsigned int cd = staging[i];
        int r = cd >> 16;
        int c = cd & 0xffff;
        float dx = x[r * 3 + 0] - x[c * 3 + 0];
        float dy = x[r * 3 + 1] - x[c * 3 + 1];
        float dz = x[r * 3 + 2] - x[c * 3 + 2];
        float dist = sqrtf(dx * dx + dy * dy + dz * dz);
        int pos = atomicAdd(&cur[r & 63], 1);
        uint2 rr; rr.x = (unsigned int)c; rr.y = __float_as_uint(dist);
        erec[pos] = rr;
    }
}

// ---------------------------------------------------------------------------
// K4: per-node gather (bf16 xb rows + bf16 table) + mean -> xb[:,128:256] bf16.
// One block per node; 4 subwaves split edges; shfl broadcast + 4-edge unroll.
__global__ __launch_bounds__(256) void agg_kernel(
        const int* __restrict__ offsets, const uint2* __restrict__ erec,
        const unsigned short* __restrict__ Tb, unsigned short* __restrict__ xb) {
    __shared__ float red[3][DIM];
    int wave = threadIdx.x >> 6;
    int lane = threadIdx.x & 63;
    int node = blockIdx.x;
    int off0 = offsets[node], off1 = offsets[node + 1];
    int deg = off1 - off0;
    int qd = (deg + 3) >> 2;
    int start = off0 + wave * qd;
    int end = min(off1, start + qd);
    float a0 = 0.f, a1 = 0.f;
    int dd = lane * 2;

    for (int base = start; base < end; base += 64) {
        int m = end - base; if (m > 64) m = 64;
        int myc = 0; float myd = 0.f;
        if (lane < m) {
            uint2 r = erec[base + lane];
            myc = (int)r.x; myd = __uint_as_float(r.y);
        }
        int i = 0;
        for (; i + 4 <= m; i += 4) {
            int   c0 = __shfl(myc, i + 0), c1 = __shfl(myc, i + 1);
            int   c2 = __shfl(myc, i + 2), c3 = __shfl(myc, i + 3);
            float u0 = __shfl(myd, i + 0) * TINV;
            float u1 = __shfl(myd, i + 1) * TINV;
            float u2 = __shfl(myd, i + 2) * TINV;
            float u3 = __shfl(myd, i + 3) * TINV;
            int k0 = min((int)u0, TK - 2); float f0 = u0 - (float)k0;
            int k1 = min((int)u1, TK - 2); float f1 = u1 - (float)k1;
            int k2 = min((int)u2, TK - 2); float f2 = u2 - (float)k2;
            int k3 = min((int)u3, TK - 2); float f3 = u3 - (float)k3;
            unsigned int h0 = *(const unsigned int*)&xb[c0 * 256 + dd];
            unsigned int h1 = *(const unsigned int*)&xb[c1 * 256 + dd];
            unsigned int h2 = *(const unsigned int*)&xb[c2 * 256 + dd];
            unsigned int h3 = *(const unsigned int*)&xb[c3 * 256 + dd];
            unsigned int A0 = *(const unsigned int*)&Tb[k0 * DIM + dd];
            unsigned int B0 = *(const unsigned int*)&Tb[k0 * DIM + DIM + dd];
            unsigned int A1 = *(const unsigned int*)&Tb[k1 * DIM + dd];
            unsigned int B1 = *(const unsigned int*)&Tb[k1 * DIM + DIM + dd];
            unsigned int A2 = *(const unsigned int*)&Tb[k2 * DIM + dd];
            unsigned int B2 = *(const unsigned int*)&Tb[k2 * DIM + DIM + dd];
            unsigned int A3 = *(const unsigned int*)&Tb[k3 * DIM + dd];
            unsigned int B3 = *(const unsigned int*)&Tb[k3 * DIM + DIM + dd];
            float ax, bx, ay, by;
            ax = bf2f((unsigned short)A0); bx = bf2f((unsigned short)(A0 >> 16));
            ay = bf2f((unsigned short)B0); by = bf2f((unsigned short)(B0 >> 16));
            a0 += bf2f((unsigned short)h0)         * (ax + (ay - ax) * f0);
            a1 += bf2f((unsigned short)(h0 >> 16)) * (bx + (by - bx) * f0);
            ax = bf2f((unsigned short)A1); bx = bf2f((unsigned short)(A1 >> 16));
            ay = bf2f((unsigned short)B1); by = bf2f((unsigned short)(B1 >> 16));
            a0 += bf2f((unsigned short)h1)         * (ax + (ay - ax) * f1);
            a1 += bf2f((unsigned short)(h1 >> 16)) * (bx + (by - bx) * f1);
            ax = bf2f((unsigned short)A2); bx = bf2f((unsigned short)(A2 >> 16));
            ay = bf2f((unsigned short)B2); by = bf2f((unsigned short)(B2 >> 16));
            a0 += bf2f((unsigned short)h2)         * (ax + (ay - ax) * f2);
            a1 += bf2f((unsigned short)(h2 >> 16)) * (bx + (by - bx) * f2);
            ax = bf2f((unsigned short)A3); bx = bf2f((unsigned short)(A3 >> 16));
            ay = bf2f((unsigned short)B3); by = bf2f((unsigned short)(B3 >> 16));
            a0 += bf2f((unsigned short)h3)         * (ax + (ay - ax) * f3);
            a1 += bf2f((unsigned short)(h3 >> 16)) * (bx + (by - bx) * f3);
        }
        for (; i < m; ++i) {
            int   c = __shfl(myc, i);
            float u = __shfl(myd, i) * TINV;
            int k = min((int)u, TK - 2);
            float f = u - (float)k;
            unsigned int hv = *(const unsigned int*)&xb[c * 256 + dd];
            unsigned int Av = *(const unsigned int*)&Tb[k * DIM + dd];
            unsigned int Bv = *(const unsigned int*)&Tb[k * DIM + DIM + dd];
            float ax = bf2f((unsigned short)Av), bx = bf2f((unsigned short)(Av >> 16));
            float ay = bf2f((unsigned short)Bv), by = bf2f((unsigned short)(Bv >> 16));
            a0 += bf2f((unsigned short)hv)         * (ax + (ay - ax) * f);
            a1 += bf2f((unsigned short)(hv >> 16)) * (bx + (by - bx) * f);
        }
    }

    if (wave > 0) { red[wave - 1][dd] = a0; red[wave - 1][dd + 1] = a1; }
    __syncthreads();
    if (wave == 0) {
        a0 += red[0][dd]     + red[1][dd]     + red[2][dd];
        a1 += red[0][dd + 1] + red[1][dd + 1] + red[2][dd + 1];
        float inv = 1.0f / (float)max(deg, 1);
        unsigned int packed = (unsigned int)f2bf(a0 * inv)
                            | ((unsigned int)f2bf(a1 * inv) << 16);
        *(unsigned int*)&xb[node * 256 + 128 + dd] = packed;
    }
}

// ---------------------------------------------------------------------------
// K5: fused node update via MFMA bf16 (m89-verified layouts).
__global__ __launch_bounds__(256) void node_kernel(
        const unsigned short* __restrict__ xb, const unsigned short* __restrict__ w3t,
        const float* __restrict__ b3, const float* __restrict__ gamma,
        const float* __restrict__ beta, const unsigned short* __restrict__ w4t,
        const float* __restrict__ b4, float* __restrict__ out) {
    __shared__ __align__(16) unsigned short a_lds[64][264];  // act, bf16, 33 KB
    __shared__ float part_s[4][64];
    __shared__ float part_q[4][64];
    int t = threadIdx.x;
    int wv = t >> 6, lane = t & 63;
    int q = lane >> 4, l15 = lane & 15;
    int n0 = blockIdx.x * 64;

    // ---- GEMM1: acc[mt][nt] = X[64x256] @ W3 (this wave's 64-col slice)
    f32x4 acc[4][4];
#pragma unroll
    for (int mt = 0; mt < 4; ++mt)
#pragma unroll
        for (int nt = 0; nt < 4; ++nt)
            acc[mt][nt] = (f32x4){0.f, 0.f, 0.f, 0.f};

    for (int kc = 0; kc < 8; ++kc) {
        bf16x8 a[4];
#pragma unroll
        for (int mt = 0; mt < 4; ++mt)
            a[mt] = *(const bf16x8*)&xb[(n0 + mt * 16 + l15) * 256 + kc * 32 + q * 8];
#pragma unroll
        for (int nt = 0; nt < 4; ++nt) {
            bf16x8 b = *(const bf16x8*)&w3t[(wv * 64 + nt * 16 + l15) * 256 + kc * 32 + q * 8];
#pragma unroll
            for (int mt = 0; mt < 4; ++mt)
                acc[mt][nt] = __builtin_amdgcn_mfma_f32_16x16x32_bf16(a[mt], b, acc[mt][nt], 0, 0, 0);
        }
    }

    // ---- bias + LN stats
    float b3v[4], gv[4], bv[4];
#pragma unroll
    for (int nt = 0; nt < 4; ++nt) {
        int col = wv * 64 + nt * 16 + l15;
        b3v[nt] = b3[col]; gv[nt] = gamma[col]; bv[nt] = beta[col];
    }
    float s[4][4], ss[4][4];   // [mt][reg]
#pragma unroll
    for (int mt = 0; mt < 4; ++mt)
#pragma unroll
        for (int reg = 0; reg < 4; ++reg) {
            float su = 0.f, sq = 0.f;
#pragma unroll
            for (int nt = 0; nt < 4; ++nt) {
                float v = acc[mt][nt][reg] + b3v[nt];
                acc[mt][nt][reg] = v;
                su += v; sq += v * v;
            }
            s[mt][reg] = su; ss[mt][reg] = sq;
        }
#pragma unroll
    for (int off = 1; off < 16; off <<= 1) {
#pragma unroll
        for (int mt = 0; mt < 4; ++mt)
#pragma unroll
            for (int reg = 0; reg < 4; ++reg) {
                s[mt][reg]  += __shfl_xor(s[mt][reg],  off, 64);
                ss[mt][reg] += __shfl_xor(ss[mt][reg], off, 64);
            }
    }
    if (l15 == 0) {
#pragma unroll
        for (int mt = 0; mt < 4; ++mt)
#pragma unroll
            for (int reg = 0; reg < 4; ++reg) {
                int r = mt * 16 + q * 4 + reg;
                part_s[wv][r] = s[mt][reg];
                part_q[wv][r] = ss[mt][reg];
            }
    }
    __syncthreads();

    // ---- LN + SiLU -> bf16 act in LDS (A-operand layout [m][k])
#pragma unroll
    for (int mt = 0; mt < 4; ++mt)
#pragma unroll
        for (int reg = 0; reg < 4; ++reg) {
            int r = mt * 16 + q * 4 + reg;
            float st = part_s[0][r] + part_s[1][r] + part_s[2][r] + part_s[3][r];
            float qt = part_q[0][r] + part_q[1][r] + part_q[2][r] + part_q[3][r];
            float mu = st * (1.0f / 256.0f);
            float var = qt * (1.0f / 256.0f) - mu * mu;
            float rs = rsqrtf(var + LN_EPS);
#pragma unroll
            for (int nt = 0; nt < 4; ++nt) {
                float un = (acc[mt][nt][reg] - mu) * rs * gv[nt] + bv[nt];
                float act = un / (1.0f + expf(-un));
                a_lds[r][wv * 64 + nt * 16 + l15] = f2bf(act);
            }
        }
    __syncthreads();

    // ---- GEMM2: out[64,128] = act @ W4; this wave: cols wv*32 .. wv*32+31
    f32x4 acc2[4][2];
#pragma unroll
    for (int mt = 0; mt < 4; ++mt)
#pragma unroll
        for (int nt = 0; nt < 2; ++nt)
            acc2[mt][nt] = (f32x4){0.f, 0.f, 0.f, 0.f};
    for (int kc = 0; kc < 8; ++kc) {
        bf16x8 a[4];
#pragma unroll
        for (int mt = 0; mt < 4; ++mt)
            a[mt] = *(const bf16x8*)&a_lds[mt * 16 + l15][kc * 32 + q * 8];
#pragma unroll
        for (int nt = 0; nt < 2; ++nt) {
            bf16x8 b = *(const bf16x8*)&w4t[(wv * 32 + nt * 16 + l15) * 256 + kc * 32 + q * 8];
#pragma unroll
            for (int mt = 0; mt < 4; ++mt)
                acc2[mt][nt] = __builtin_amdgcn_mfma_f32_16x16x32_bf16(a[mt], b, acc2[mt][nt], 0, 0, 0);
        }
    }
    float b4v[2];
#pragma unroll
    for (int nt = 0; nt < 2; ++nt) b4v[nt] = b4[wv * 32 + nt * 16 + l15];
#pragma unroll
    for (int mt = 0; mt < 4; ++mt)
#pragma unroll
        for (int nt = 0; nt < 2; ++nt)
#pragma unroll
            for (int reg = 0; reg < 4; ++reg) {
                int node = n0 + mt * 16 + q * 4 + reg;
                out[node * DIM + wv * 32 + nt * 16 + l15] = acc2[mt][nt][reg] + b4v[nt];
            }
}

// ---------------------------------------------------------------------------
extern "C" void kernel_launch(void* const* d_in, const int* in_sizes, int n_in,
                              void* d_out, int out_size, void* d_ws, size_t ws_size,
                              hipStream_t stream) {
    const float* x     = (const float*)d_in[0];
    const float* h     = (const float*)d_in[1];
    const int*   ei    = (const int*)d_in[2];
    const float* W1    = (const float*)d_in[4];
    const float* b1    = (const float*)d_in[5];
    const float* W2    = (const float*)d_in[6];
    const float* b2    = (const float*)d_in[7];
    const float* W3    = (const float*)d_in[8];
    const float* b3    = (const float*)d_in[9];
    const float* gamma = (const float*)d_in[10];
    const float* beta  = (const float*)d_in[11];
    const float* W4    = (const float*)d_in[12];
    const float* b4    = (const float*)d_in[13];
    float* out = (float*)d_out;
    int nE = in_sizes[2] / 2;

    char* ws = (char*)d_ws;
    unsigned short* Tb  = (unsigned short*)ws; ws += (size_t)TK * DIM * 2;       // 512 KB
    unsigned short* w3t = (unsigned short*)ws; ws += (size_t)HID * HID * 2;      // 128 KB
    unsigned short* w4t = (unsigned short*)ws; ws += (size_t)DIM * HID * 2;      // 64 KB
    unsigned short* xb  = (unsigned short*)ws; ws += (size_t)BN_NODES * 256 * 2; // 8 MB
    int*   counts     = (int*)ws;          ws += (size_t)BN_NODES * 4;
    int*   offsets    = (int*)ws;          ws += (size_t)(BN_NODES + 128) * 4;
    int*   bin_cursor = (int*)ws;          ws += 256 * 4;
    unsigned int* staging = (unsigned int*)ws; ws += (size_t)nE * 4;             // 2 MB
    uint2* erec       = (uint2*)ws;        ws += (size_t)nE * 8;                 // 4 MB

    int histBlocks = (nE + 255) / 256;
    int binABlocks = (nE + EPB - 1) / EPB;
    hipMemsetAsync(counts, 0, (size_t)BN_NODES * 4, stream);
    prep_kernel<<<1376 + histBlocks, 256, 0, stream>>>(W1, b1, W2, b2, W3, W4, h, ei,
                                                       Tb, w3t, w4t, xb, counts, nE);
    scan_kernel<<<1, 1024, 0, stream>>>(counts, offsets, bin_cursor);
    binA_kernel<<<binABlocks, 256, 0, stream>>>(ei, bin_cursor, staging, nE);
    binB_kernel<<<256, 256, 0, stream>>>(staging, x, offsets, erec);
    agg_kernel<<<BN_NODES, 256, 0, stream>>>(offsets, erec, Tb, xb);
    node_kernel<<<BN_NODES / 64, 256, 0, stream>>>(xb, w3t, b3, gamma, beta, w4t, b4, out);
}